// Round 1
// baseline (1053.498 us; speedup 1.0000x reference)
//
#include <hip/hip_runtime.h>
#include <hip/hip_bf16.h>
#include <cstdint>

#define H      192
#define TWOH   384
#define PP     64
#define RADIUS 0.42f
#define BSCALE 0.18f
#define NEGINF -1e9f

#define MT  64    // rows per block
#define KT  32    // K chunk
#define AS  68    // As_t[32][68]  (transposed A tile, stride mult-of-4 for b128 reads)
#define BSD 132   // Bs[32][132]
#define LSD 132   // Ls[64][132]  (logits, later weights)

__device__ __forceinline__ float waveSum(float v) {
#pragma unroll
  for (int o = 32; o; o >>= 1) v += __shfl_xor(v, o, 64);
  return v;
}
__device__ __forceinline__ float waveMax(float v) {
#pragma unroll
  for (int o = 32; o; o >>= 1) v = fmaxf(v, __shfl_xor(v, o, 64));
  return v;
}
__device__ __forceinline__ float waveMin(float v) {
#pragma unroll
  for (int o = 32; o; o >>= 1) v = fminf(v, __shfl_xor(v, o, 64));
  return v;
}

__global__ __launch_bounds__(256)
void taps_fused_kernel(const float* __restrict__ tok, const float* __restrict__ prv,
                       const float* __restrict__ Wsel, const float* __restrict__ bsel,
                       const float* __restrict__ Wbr,  const float* __restrict__ bbr,
                       const float* __restrict__ pv,   const float* __restrict__ pp,
                       float* __restrict__ out, int B) {
  __shared__ float smem[MT * LSD];           // 33792 B
  float* As = smem;                          // [KT][AS]
  float* Bs = smem + KT * AS;                // [KT][BSD]
  float* Ls = smem;                          // [MT][LSD] overlays As/Bs after GEMM

  const int t = threadIdx.x;
  const int row0 = blockIdx.x * MT;
  const int r0 = (t >> 4) * 4;               // 4 rows per thread
  const int c0 = (t & 15) * 8;               // 8 cols per thread

  float acc[4][8];
#pragma unroll
  for (int i = 0; i < 4; i++)
#pragma unroll
    for (int j = 0; j < 8; j++) acc[i][j] = 0.f;

  // ---- Phase 1: logits[64][128] = Q[64][384] @ Wcat^T ----
  for (int kc = 0; kc < TWOH; kc += KT) {
    const float* src = (kc < H) ? tok : prv;
    const int koff = (kc < H) ? kc : (kc - H);
    // A tile (64 rows x 32 k) -> transposed LDS
#pragma unroll
    for (int i = 0; i < 2; i++) {
      int slot = t + i * 256;
      int r = slot >> 3, k4 = slot & 7;
      int gr = row0 + r; if (gr >= B) gr = B - 1;
      float4 v = *(const float4*)(src + (size_t)gr * H + koff + k4 * 4);
      As[(k4 * 4 + 0) * AS + r] = v.x;
      As[(k4 * 4 + 1) * AS + r] = v.y;
      As[(k4 * 4 + 2) * AS + r] = v.z;
      As[(k4 * 4 + 3) * AS + r] = v.w;
    }
    // B tile (128 n x 32 k) -> Bs[k][n]
#pragma unroll
    for (int i = 0; i < 4; i++) {
      int slot = t + i * 256;
      int n = slot >> 3, k4 = slot & 7;
      const float* wr = (n < PP) ? (Wsel + (size_t)n * TWOH) : (Wbr + (size_t)(n - PP) * TWOH);
      float4 v = *(const float4*)(wr + kc + k4 * 4);
      Bs[(k4 * 4 + 0) * BSD + n] = v.x;
      Bs[(k4 * 4 + 1) * BSD + n] = v.y;
      Bs[(k4 * 4 + 2) * BSD + n] = v.z;
      Bs[(k4 * 4 + 3) * BSD + n] = v.w;
    }
    __syncthreads();
#pragma unroll
    for (int k = 0; k < KT; k++) {
      float4 a  = *(const float4*)&As[k * AS + r0];
      float4 b0 = *(const float4*)&Bs[k * BSD + c0];
      float4 b1 = *(const float4*)&Bs[k * BSD + c0 + 4];
      float av[4] = {a.x, a.y, a.z, a.w};
      float bv[8] = {b0.x, b0.y, b0.z, b0.w, b1.x, b1.y, b1.z, b1.w};
#pragma unroll
      for (int i = 0; i < 4; i++)
#pragma unroll
        for (int j = 0; j < 8; j++) acc[i][j] = fmaf(av[i], bv[j], acc[i][j]);
    }
    __syncthreads();
  }

  // bias + park logits in LDS
  float bias[8];
#pragma unroll
  for (int j = 0; j < 8; j++) {
    int n = c0 + j;
    bias[j] = (n < PP) ? bsel[n] : bbr[n - PP];
  }
#pragma unroll
  for (int i = 0; i < 4; i++)
#pragma unroll
    for (int j = 0; j < 8; j++) Ls[(r0 + i) * LSD + c0 + j] = acc[i][j] + bias[j];
  __syncthreads();

  // ---- Phase 3: per-row postprocess; wave w handles rows w*16..w*16+15 ----
  const int wv = t >> 6;
  const int lane = t & 63;                   // = patch index
  const float px = pp[lane * 3 + 0], py = pp[lane * 3 + 1], pz = pp[lane * 3 + 2];
  const size_t oW = (size_t)B * 192, oA = (size_t)B * 256, oLM = (size_t)B * 259,
               oBM = (size_t)B * 260, oMD = (size_t)B * 261, oR = (size_t)B * 262,
               oS = (size_t)B * 263;

#pragma unroll 1
  for (int i = 0; i < 16; i++) {
    int r = wv * 16 + i;
    int rowg = row0 + r;
    bool valid = rowg < B;
    float ls = Ls[r * LSD + lane];
    float lb = Ls[r * LSD + 64 + lane];
    // softmax over sel logits
    float m = waveMax(ls);
    float e = __expf(ls - m);
    float s = waveSum(e);
    float bw = e / s;
    // anchor position
    float ax = waveSum(bw * px);
    float ay = waveSum(bw * py);
    float az = waveSum(bw * pz);
    float dx = ax - px, dy = ay - py, dz = az - pz;
    float d2 = dx * dx + dy * dy + dz * dz;
    float dist = sqrtf(d2);
    float dmin = waveMin(dist);
    unsigned long long nmask = __ballot(dist == dmin);
    int nearest = __builtin_ctzll(nmask);
    bool local = (dist <= RADIUS) || (lane == nearest);
    float lk = __expf(d2 * (-1.0f / (2.0f * RADIUS * RADIUS)));
    float bl = local ? NEGINF : lb;
    // stable top-6 (lower index first on ties, like jax.lax.top_k)
    float rem = bl;
    float tv[6];
    int rank = -1;
#pragma unroll
    for (int it = 0; it < 6; ++it) {
      float mv = waveMax(rem);
      tv[it] = mv;
      unsigned long long mk = __ballot(rem == mv);
      int sel = __builtin_ctzll(mk);
      if (lane == sel) { rank = it; rem = -3.0e38f; }
    }
    float m6 = tv[0];
    float esum = 0.f;
#pragma unroll
    for (int it = 0; it < 6; ++it) esum += __expf(tv[it] - m6);
    float sb = (rank >= 0) ? (__expf(bl - m6) / esum) : 0.f;
    float lmf = local ? 1.f : 0.f;
    float mixed = bw * lk * lmf + BSCALE * sb;
    float tot = waveSum(mixed);
    float w = mixed / fmaxf(tot, 1e-6f);
    if (valid) out[oW + (size_t)rowg * 64 + lane] = w;
    float lmass = waveSum(w * lmf);
    float bmass = waveSum(w * (1.f - lmf));
    float md = waveSum(w * dist);
    if (valid && lane == 0) {
      out[oA + (size_t)rowg * 3 + 0] = ax;
      out[oA + (size_t)rowg * 3 + 1] = ay;
      out[oA + (size_t)rowg * 3 + 2] = az;
      out[oLM + rowg] = lmass;
      out[oBM + rowg] = bmass;
      out[oMD + rowg] = md;
      out[oR + rowg] = RADIUS;
      out[oS + rowg] = BSCALE;
    }
    Ls[r * LSD + lane] = w;   // park weights for phase 4
  }
  __syncthreads();

  // ---- Phase 4: patch_state[64][192] = Ws[64][64] @ pv[64][192] ----
  const int c0b = (t & 15) * 12;
  float acc2[4][12];
#pragma unroll
  for (int i = 0; i < 4; i++)
#pragma unroll
    for (int j = 0; j < 12; j++) acc2[i][j] = 0.f;

#pragma unroll 4
  for (int k = 0; k < PP; k++) {
    float wk[4];
#pragma unroll
    for (int i = 0; i < 4; i++) wk[i] = Ls[(r0 + i) * LSD + k];
    float4 p0 = *(const float4*)(pv + (size_t)k * H + c0b);
    float4 p1 = *(const float4*)(pv + (size_t)k * H + c0b + 4);
    float4 p2 = *(const float4*)(pv + (size_t)k * H + c0b + 8);
    float pvv[12] = {p0.x, p0.y, p0.z, p0.w, p1.x, p1.y, p1.z, p1.w, p2.x, p2.y, p2.z, p2.w};
#pragma unroll
    for (int i = 0; i < 4; i++)
#pragma unroll
      for (int j = 0; j < 12; j++) acc2[i][j] = fmaf(wk[i], pvv[j], acc2[i][j]);
  }
#pragma unroll
  for (int i = 0; i < 4; i++) {
    int rowg = row0 + r0 + i;
    if (rowg < B) {
      float* o = out + (size_t)rowg * H + c0b;
      *(float4*)(o + 0) = make_float4(acc2[i][0], acc2[i][1], acc2[i][2], acc2[i][3]);
      *(float4*)(o + 4) = make_float4(acc2[i][4], acc2[i][5], acc2[i][6], acc2[i][7]);
      *(float4*)(o + 8) = make_float4(acc2[i][8], acc2[i][9], acc2[i][10], acc2[i][11]);
    }
  }
}

extern "C" void kernel_launch(void* const* d_in, const int* in_sizes, int n_in,
                              void* d_out, int out_size, void* d_ws, size_t ws_size,
                              hipStream_t stream) {
  const float* tok  = (const float*)d_in[0];
  const float* prv  = (const float*)d_in[1];
  const float* Wsel = (const float*)d_in[2];
  const float* bsel = (const float*)d_in[3];
  const float* Wbr  = (const float*)d_in[4];
  const float* bbr  = (const float*)d_in[5];
  const float* pv   = (const float*)d_in[6];
  const float* pp   = (const float*)d_in[7];
  float* out = (float*)d_out;
  const int B = in_sizes[0] / H;
  const int grid = (B + MT - 1) / MT;
  hipLaunchKernelGGL(taps_fused_kernel, dim3(grid), dim3(256), 0, stream,
                     tok, prv, Wsel, bsel, Wbr, bbr, pv, pp, out, B);
}